// Round 13
// baseline (284.880 us; speedup 1.0000x reference)
//
#include <hip/hip_runtime.h>

// GCN pull-mode, round 13. r12 structure (4 fused aggregate kernels, 7
// dispatches) + two micro-fixes:
//  - LDS padding: sAgg stride 64->72 halfs, sT 96->104, gemm4 sT 32->40.
//    (r12's 750k SQ_LDS_BANK_CONFLICT = 16-way conflicts on MFMA a-frag
//    loads at 128B row stride.)
//  - mega1 MFMA tail spread: chain1 over 6 waves (1 col tile each),
//    chain2 over 4 waves (was 2 waves x 3/2 tiles).
// Cost model: each aggregate is line-request bound (E=1.6M random 128B line
// requests ~= 50us regardless of F); 4 aggregates + build + gaps ~= 260us.

#define TPB 256
#define NBUCK 782    // ceil(100000/128)
#define BCAP 3072    // fixed slot size; mean 2047, +22 sigma headroom
#define CHUNK 8192   // edges per block in scatter

typedef __attribute__((ext_vector_type(8))) _Float16 half8;
typedef __attribute__((ext_vector_type(4))) _Float16 half4;
typedef __attribute__((ext_vector_type(4))) float f32x4;

// --- Scatter packed edges into fixed bucket slots ---
__global__ void bscatter_kernel(const int* __restrict__ src, const int* __restrict__ dst,
                                int* __restrict__ bcur, int* __restrict__ bsort, int E) {
    __shared__ int h[NBUCK];
    __shared__ int cur[NBUCK];
    int tid = threadIdx.x;
    for (int i = tid; i < NBUCK; i += blockDim.x) h[i] = 0;
    __syncthreads();
    int base = blockIdx.x * CHUNK;
    int lim = min(base + CHUNK, E);
    for (int e = base + tid; e < lim; e += blockDim.x)
        atomicAdd(&h[dst[e] >> 7], 1);
    __syncthreads();
    for (int i = tid; i < NBUCK; i += blockDim.x)
        cur[i] = h[i] ? (atomicAdd(&bcur[i], h[i]) + i * BCAP) : 0;
    __syncthreads();
    for (int e = base + tid; e < lim; e += blockDim.x) {
        int d = dst[e];
        int pos = atomicAdd(&cur[d >> 7], 1);
        bsort[pos] = ((d & 127) << 17) | src[e];  // src < 2^17
    }
}

// --- Per-bucket local sort -> csr slot; rowstart/rowdeg/dis; X prescale ---
__global__ __launch_bounds__(256) void bbuild_kernel(
        const int* __restrict__ bcur, const int* __restrict__ bsort,
        int* __restrict__ csr, int* __restrict__ rowstart, int* __restrict__ rowdeg,
        float* __restrict__ dis,
        const float4* __restrict__ x4, _Float16* __restrict__ xs,
        int N) {
    __shared__ int ebuf[BCAP];
    __shared__ int obuf[BCAP];
    __shared__ int cnt[128];
    __shared__ int off[129];
    __shared__ float sdis[128];
    int b = blockIdx.x;
    int tid = threadIdx.x;
    int ebase = b * BCAP;
    int n = min(bcur[b], BCAP);
    if (tid < 128) cnt[tid] = 0;
    __syncthreads();
    for (int i = tid; i < n; i += 256) {
        int p = bsort[ebase + i];
        ebuf[i] = p;
        atomicAdd(&cnt[p >> 17], 1);
    }
    __syncthreads();
    if (tid < 64) {
        int lane = tid;
        int v0 = cnt[lane];
#pragma unroll
        for (int d = 1; d < 64; d <<= 1) { int u = __shfl_up(v0, d, 64); if (lane >= d) v0 += u; }
        off[lane + 1] = v0;
        int tot0 = __shfl(v0, 63, 64);
        int v1 = cnt[64 + lane];
#pragma unroll
        for (int d = 1; d < 64; d <<= 1) { int u = __shfl_up(v1, d, 64); if (lane >= d) v1 += u; }
        off[64 + lane + 1] = tot0 + v1;
        if (lane == 0) off[0] = 0;
    }
    __syncthreads();
    int node0 = b << 7;
    if (tid < 128 && node0 + tid < N) {
        int deg = off[tid + 1] - off[tid];
        rowstart[node0 + tid] = ebase + off[tid];
        rowdeg[node0 + tid] = deg;
        float d = rsqrtf((float)deg + 1.0f);
        dis[node0 + tid] = d;
        sdis[tid] = d;
    }
    if (tid < 128) cnt[tid] = off[tid];  // reuse as cursor
    __syncthreads();
    for (int i = tid; i < n; i += 256) {
        int p = ebuf[i];
        int pos = atomicAdd(&cnt[p >> 17], 1);
        obuf[pos] = p & 0x1FFFF;
    }
    __syncthreads();
    for (int i = tid; i < n; i += 256)
        csr[ebase + i] = obuf[i];
    // fused prescale: xs[node] = half(x[node] * dis[node]) for this bucket
    for (int i = tid; i < 128 * 16; i += 256) {
        int r = i >> 4, c = i & 15;
        int node = node0 + r;
        if (node >= N) break;
        float d = sdis[r];
        float4 v = x4[(size_t)node * 16 + c];
        half4 h;
        h[0] = (_Float16)(v.x * d); h[1] = (_Float16)(v.y * d);
        h[2] = (_Float16)(v.z * d); h[3] = (_Float16)(v.w * d);
        *(half4*)(xs + (size_t)node * 64 + 4 * c) = h;
    }
}

// Transpose + fp16-convert weights (Wt[m*K+k] = half(W[k*M+m])); zero bcur.
// Sections: W1t 96x64 @0, W2t 64x96 @6144, W3t 32x64 @12288, W4t 16x32 @14336.
__global__ void wprep_kernel(const float* __restrict__ W1, const float* __restrict__ W2,
                             const float* __restrict__ W3, const float* __restrict__ W4,
                             _Float16* __restrict__ wt, int* __restrict__ bcur) {
    int t = blockIdx.x * blockDim.x + threadIdx.x;
    if (t < 788) bcur[t] = 0;
    if (t < 6144) {
        int m = t / 64, k = t % 64;
        wt[t] = (_Float16)W1[k * 96 + m];
    } else if (t < 12288) {
        int i = t - 6144; int m = i / 96, k = i % 96;
        wt[t] = (_Float16)W2[k * 64 + m];
    } else if (t < 14336) {
        int i = t - 12288; int m = i / 64, k = i % 64;
        wt[t] = (_Float16)W3[k * 32 + m];
    } else if (t < 14848) {
        int i = t - 14336; int m = i / 32, k = i % 32;
        wt[t] = (_Float16)W4[k * 16 + m];
    }
}

#define SAS 72   // sAgg row stride (halfs): 64+8, bank stride 4 -> <=2-way
#define STS 104  // sT row stride (halfs): 96+8

// mega1: 16 rows/block (8 waves x 2 rows). agg64(xs)*dis -> sAgg fp16 ->
// chain1 (6 waves, 1 col tile each): @W1+b1,relu -> sT -> chain2 (4 waves):
// @W2,*dis -> Z2 fp16.
__global__ __launch_bounds__(512) void mega1_kernel(
        const _Float16* __restrict__ hs, const int* __restrict__ rowstart,
        const int* __restrict__ rowdeg, const int* __restrict__ csr,
        const float* __restrict__ dis,
        const _Float16* __restrict__ W1t, const float* __restrict__ b1,
        const _Float16* __restrict__ W2t,
        _Float16* __restrict__ Z2, int N) {
    __shared__ _Float16 sAgg[16 * SAS];
    __shared__ _Float16 sT[16 * STS];
    int tid = threadIdx.x;
    int wid = tid >> 6;
    int lane = tid & 63;
    int srow = lane >> 5;    // RPW=2: SPAN=32
    int l2 = lane & 31;
    int g = l2 >> 3;         // LPR=8, G=4
    int q = l2 & 7;
    int rbase = blockIdx.x * 16;
    int br = wid * 2 + srow;
    int row = rbase + br;

    if (row < N) {
        int start = rowstart[row];
        int end = start + rowdeg[row];
        float a0[8] = {}, a1[8] = {};
        if (g == 0) {  // self loop
            half8 v = *(const half8*)(hs + (size_t)row * 64 + 8 * q);
#pragma unroll
            for (int j = 0; j < 8; ++j) a0[j] = (float)v[j];
        }
        int e = start + g;
        for (; e + 4 < end; e += 8) {
            int s0 = csr[e];
            int s1 = csr[e + 4];
            half8 v0 = *(const half8*)(hs + (size_t)s0 * 64 + 8 * q);
            half8 v1 = *(const half8*)(hs + (size_t)s1 * 64 + 8 * q);
#pragma unroll
            for (int j = 0; j < 8; ++j) { a0[j] += (float)v0[j]; a1[j] += (float)v1[j]; }
        }
        for (; e < end; e += 4) {
            int s = csr[e];
            half8 v = *(const half8*)(hs + (size_t)s * 64 + 8 * q);
#pragma unroll
            for (int j = 0; j < 8; ++j) a0[j] += (float)v[j];
        }
#pragma unroll
        for (int j = 0; j < 8; ++j) a0[j] += a1[j];
#pragma unroll
        for (int m = 8; m < 32; m <<= 1) {
#pragma unroll
            for (int j = 0; j < 8; ++j) a0[j] += __shfl_xor(a0[j], m, 64);
        }
        if (g == 0) {
            float d = dis[row];
#pragma unroll
            for (int j = 0; j < 8; ++j)
                sAgg[br * SAS + 8 * q + j] = (_Float16)(a0[j] * d);
        }
    }
    __syncthreads();
    int quad = lane >> 4, m16 = lane & 15;
    if (wid < 6) {
        // chain1: aggX(16x64) @ W1 (64->96), +b1, relu -> sT; 1 col tile/wave
        half8 a[2];
        a[0] = *(const half8*)(sAgg + m16 * SAS + quad * 8);
        a[1] = *(const half8*)(sAgg + m16 * SAS + 32 + quad * 8);
        int ct = wid;
        f32x4 c = {0.f, 0.f, 0.f, 0.f};
#pragma unroll
        for (int kt = 0; kt < 2; ++kt) {
            half8 b = *(const half8*)(W1t + (size_t)(ct * 16 + m16) * 64 + kt * 32 + quad * 8);
            c = __builtin_amdgcn_mfma_f32_16x16x32_f16(a[kt], b, c, 0, 0, 0);
        }
        int col = ct * 16 + m16;
        float bb = b1[col];
#pragma unroll
        for (int r = 0; r < 4; ++r)
            sT[(quad * 4 + r) * STS + col] = (_Float16)fmaxf(c[r] + bb, 0.f);
    }
    __syncthreads();
    if (wid < 4) {
        // chain2: t1(16x96) @ W2 (96->64), *dis -> Z2; 1 col tile/wave
        half8 a2[3];
#pragma unroll
        for (int kt = 0; kt < 3; ++kt)
            a2[kt] = *(const half8*)(sT + m16 * STS + kt * 32 + quad * 8);
        float dv[4];
#pragma unroll
        for (int r = 0; r < 4; ++r) {
            int orow = rbase + quad * 4 + r;
            dv[r] = (orow < N) ? dis[orow] : 0.f;
        }
        int ct = wid;
        f32x4 c = {0.f, 0.f, 0.f, 0.f};
#pragma unroll
        for (int kt = 0; kt < 3; ++kt) {
            half8 b = *(const half8*)(W2t + (size_t)(ct * 16 + m16) * 96 + kt * 32 + quad * 8);
            c = __builtin_amdgcn_mfma_f32_16x16x32_f16(a2[kt], b, c, 0, 0, 0);
        }
        int col = ct * 16 + m16;
#pragma unroll
        for (int r = 0; r < 4; ++r) {
            int orow = rbase + quad * 4 + r;
            if (orow < N)
                Z2[(size_t)orow * 64 + col] = (_Float16)(c[r] * dv[r]);
        }
    }
}

// mega2: agg64(Z2), t2 = relu(dis*sum + b2) -> sAgg fp16 ->
// waves 0-1: MFMA @W3 (*dis) -> Z3 fp16 (32 wide).
__global__ __launch_bounds__(512) void mega2_kernel(
        const _Float16* __restrict__ hs, const int* __restrict__ rowstart,
        const int* __restrict__ rowdeg, const int* __restrict__ csr,
        const float* __restrict__ dis, const float* __restrict__ b2,
        const _Float16* __restrict__ W3t,
        _Float16* __restrict__ Z3, int N) {
    __shared__ _Float16 sAgg[16 * SAS];
    int tid = threadIdx.x;
    int wid = tid >> 6;
    int lane = tid & 63;
    int srow = lane >> 5;
    int l2 = lane & 31;
    int g = l2 >> 3;
    int q = l2 & 7;
    int rbase = blockIdx.x * 16;
    int br = wid * 2 + srow;
    int row = rbase + br;

    if (row < N) {
        int start = rowstart[row];
        int end = start + rowdeg[row];
        float a0[8] = {}, a1[8] = {};
        if (g == 0) {
            half8 v = *(const half8*)(hs + (size_t)row * 64 + 8 * q);
#pragma unroll
            for (int j = 0; j < 8; ++j) a0[j] = (float)v[j];
        }
        int e = start + g;
        for (; e + 4 < end; e += 8) {
            int s0 = csr[e];
            int s1 = csr[e + 4];
            half8 v0 = *(const half8*)(hs + (size_t)s0 * 64 + 8 * q);
            half8 v1 = *(const half8*)(hs + (size_t)s1 * 64 + 8 * q);
#pragma unroll
            for (int j = 0; j < 8; ++j) { a0[j] += (float)v0[j]; a1[j] += (float)v1[j]; }
        }
        for (; e < end; e += 4) {
            int s = csr[e];
            half8 v = *(const half8*)(hs + (size_t)s * 64 + 8 * q);
#pragma unroll
            for (int j = 0; j < 8; ++j) a0[j] += (float)v[j];
        }
#pragma unroll
        for (int j = 0; j < 8; ++j) a0[j] += a1[j];
#pragma unroll
        for (int m = 8; m < 32; m <<= 1) {
#pragma unroll
            for (int j = 0; j < 8; ++j) a0[j] += __shfl_xor(a0[j], m, 64);
        }
        if (g == 0) {
            float d = dis[row];
#pragma unroll
            for (int j = 0; j < 8; ++j) {
                float v = fmaxf(a0[j] * d + b2[8 * q + j], 0.f);
                sAgg[br * SAS + 8 * q + j] = (_Float16)v;
            }
        }
    }
    __syncthreads();
    if (wid < 2) {
        int quad = lane >> 4, m16 = lane & 15;
        half8 a[2];
        a[0] = *(const half8*)(sAgg + m16 * SAS + quad * 8);
        a[1] = *(const half8*)(sAgg + m16 * SAS + 32 + quad * 8);
        int ct = wid;  // 2 col tiles total
        f32x4 c = {0.f, 0.f, 0.f, 0.f};
#pragma unroll
        for (int kt = 0; kt < 2; ++kt) {
            half8 b = *(const half8*)(W3t + (size_t)(ct * 16 + m16) * 64 + kt * 32 + quad * 8);
            c = __builtin_amdgcn_mfma_f32_16x16x32_f16(a[kt], b, c, 0, 0, 0);
        }
        int col = ct * 16 + m16;
#pragma unroll
        for (int r = 0; r < 4; ++r) {
            int orow = rbase + quad * 4 + r;
            if (orow < N)
                Z3[(size_t)orow * 32 + col] = (_Float16)(c[r] * dis[orow]);
        }
    }
}

#define ST4 40  // agg32_gemm4 sT row stride (halfs): 32+8

// Fused agg32 (+b3, relu) -> t3 in LDS -> MFMA @W4t (*dis) -> Z4 fp16.
__global__ __launch_bounds__(512) void agg32_gemm4_kernel(
        const _Float16* __restrict__ hs, const int* __restrict__ rowstart,
        const int* __restrict__ rowdeg, const int* __restrict__ csr,
        const float* __restrict__ dis, const float* __restrict__ b3,
        const _Float16* __restrict__ W4t, _Float16* __restrict__ Z4, int N) {
    __shared__ _Float16 sT[16 * ST4];
    int tid = threadIdx.x;
    int wid = tid >> 6;
    int lane = tid & 63;
    int srow = lane >> 5;   // SPAN=32
    int l2 = lane & 31;
    int g = l2 >> 2;        // LPR=4, G=8
    int q = l2 & 3;
    int rbase = blockIdx.x * 16;
    int br = wid * 2 + srow;
    int row = rbase + br;

    if (row < N) {
        int start = rowstart[row];
        int end = start + rowdeg[row];
        float a0[8] = {}, a1[8] = {};
        if (g == 0) {
            half8 v = *(const half8*)(hs + (size_t)row * 32 + 8 * q);
#pragma unroll
            for (int j = 0; j < 8; ++j) a0[j] = (float)v[j];
        }
        int e = start + g;
        for (; e + 8 < end; e += 16) {
            int s0 = csr[e];
            int s1 = csr[e + 8];
            half8 v0 = *(const half8*)(hs + (size_t)s0 * 32 + 8 * q);
            half8 v1 = *(const half8*)(hs + (size_t)s1 * 32 + 8 * q);
#pragma unroll
            for (int j = 0; j < 8; ++j) { a0[j] += (float)v0[j]; a1[j] += (float)v1[j]; }
        }
        for (; e < end; e += 8) {
            int s = csr[e];
            half8 v = *(const half8*)(hs + (size_t)s * 32 + 8 * q);
#pragma unroll
            for (int j = 0; j < 8; ++j) a0[j] += (float)v[j];
        }
#pragma unroll
        for (int j = 0; j < 8; ++j) a0[j] += a1[j];
#pragma unroll
        for (int m = 4; m < 32; m <<= 1) {
#pragma unroll
            for (int j = 0; j < 8; ++j) a0[j] += __shfl_xor(a0[j], m, 64);
        }
        if (g == 0) {
            float d = dis[row];
#pragma unroll
            for (int j = 0; j < 8; ++j) {
                float v = fmaxf(a0[j] * d + b3[8 * q + j], 0.f);
                sT[br * ST4 + 8 * q + j] = (_Float16)v;
            }
        }
    }
    __syncthreads();
    if (wid == 0) {
        int quad = lane >> 4, m16 = lane & 15;
        half8 a = *(const half8*)(sT + m16 * ST4 + quad * 8);
        half8 b = *(const half8*)(W4t + m16 * 32 + quad * 8);
        f32x4 c = {0.f, 0.f, 0.f, 0.f};
        c = __builtin_amdgcn_mfma_f32_16x16x32_f16(a, b, c, 0, 0, 0);
#pragma unroll
        for (int r = 0; r < 4; ++r) {
            int orow = rbase + quad * 4 + r;
            if (orow < N)
                Z4[(size_t)orow * 16 + m16] = (_Float16)(c[r] * dis[orow]);
        }
    }
}

// Final pull aggregation (F=16, RPW=4): out(fp32) = dis*sum + b4.
__global__ void aggregate_final_kernel(const _Float16* __restrict__ hs,
                                       const int* __restrict__ rowstart,
                                       const int* __restrict__ rowdeg,
                                       const int* __restrict__ csr,
                                       const float* __restrict__ dis,
                                       const float* __restrict__ bias,
                                       float* __restrict__ outp, int N) {
    constexpr int SPAN = 16, LPR = 2, G = 8;
    int wave = (blockIdx.x * blockDim.x + threadIdx.x) >> 6;
    int lane = threadIdx.x & 63;
    int srow = lane / SPAN;
    int l2 = lane % SPAN;
    int g = l2 / LPR;
    int q = l2 % LPR;
    int row = wave * 4 + srow;
    if (row >= N) return;
    int start = rowstart[row];
    int end = start + rowdeg[row];
    float a0[8] = {}, a1[8] = {};
    if (g == 0) {
        half8 v = *(const half8*)(hs + (size_t)row * 16 + 8 * q);
#pragma unroll
        for (int j = 0; j < 8; ++j) a0[j] = (float)v[j];
    }
    int e = start + g;
    for (; e + G < end; e += 2 * G) {
        int s0 = csr[e];
        int s1 = csr[e + G];
        half8 v0 = *(const half8*)(hs + (size_t)s0 * 16 + 8 * q);
        half8 v1 = *(const half8*)(hs + (size_t)s1 * 16 + 8 * q);
#pragma unroll
        for (int j = 0; j < 8; ++j) { a0[j] += (float)v0[j]; a1[j] += (float)v1[j]; }
    }
    for (; e < end; e += G) {
        int s = csr[e];
        half8 v = *(const half8*)(hs + (size_t)s * 16 + 8 * q);
#pragma unroll
        for (int j = 0; j < 8; ++j) a0[j] += (float)v[j];
    }
#pragma unroll
    for (int j = 0; j < 8; ++j) a0[j] += a1[j];
#pragma unroll
    for (int m = LPR; m < SPAN; m <<= 1) {
#pragma unroll
        for (int j = 0; j < 8; ++j) a0[j] += __shfl_xor(a0[j], m, 64);
    }
    if (g == 0) {
        float d = dis[row];
        float4 o0, o1;
        o0.x = a0[0] * d + bias[8 * q + 0];
        o0.y = a0[1] * d + bias[8 * q + 1];
        o0.z = a0[2] * d + bias[8 * q + 2];
        o0.w = a0[3] * d + bias[8 * q + 3];
        o1.x = a0[4] * d + bias[8 * q + 4];
        o1.y = a0[5] * d + bias[8 * q + 5];
        o1.z = a0[6] * d + bias[8 * q + 6];
        o1.w = a0[7] * d + bias[8 * q + 7];
        *(float4*)(outp + (size_t)row * 16 + 8 * q) = o0;
        *(float4*)(outp + (size_t)row * 16 + 8 * q + 4) = o1;
    }
}

static inline int cdiv(long long a, int b) { return (int)((a + b - 1) / b); }

extern "C" void kernel_launch(void* const* d_in, const int* in_sizes, int n_in,
                              void* d_out, int out_size, void* d_ws, size_t ws_size,
                              hipStream_t stream) {
    const float* x  = (const float*)d_in[0];
    const int*   ei = (const int*)d_in[1];
    const float* W1 = (const float*)d_in[2];
    const float* b1 = (const float*)d_in[3];
    const float* W2 = (const float*)d_in[4];
    const float* b2 = (const float*)d_in[5];
    const float* W3 = (const float*)d_in[6];
    const float* b3 = (const float*)d_in[7];
    const float* W4 = (const float*)d_in[8];
    const float* b4 = (const float*)d_in[9];
    float* out = (float*)d_out;

    const int N = in_sizes[0] / 64;   // 100000
    const int E = in_sizes[1] / 2;    // 1600000
    const int* src = ei;
    const int* dst = ei + E;

    int*   bcur     = (int*)d_ws;                 // 788
    int*   rowstart = bcur + 788;                 // 100096
    int*   rowdeg   = rowstart + 100096;          // 100096
    int*   csr      = rowdeg + 100096;            // NBUCK*BCAP (padded slots)
    float* dis      = (float*)(csr + NBUCK * BCAP);  // 100096
    _Float16* hP    = (_Float16*)(dis + 100096);  // N*64 halfs
    _Float16* hQ    = hP + (size_t)N * 64;        // N*64 halfs
    _Float16* wt    = hQ + (size_t)N * 64;        // 14848 halfs (Wt fp16)
    int*   bsort    = (int*)hP;  // NBUCK*BCAP ints, dead before hP's first write

    // --- build: wprep (zeros bcur + converts weights); scatter; bucket sort ---
    wprep_kernel<<<cdiv(14848, TPB), TPB, 0, stream>>>(W1, W2, W3, W4, wt, bcur);
    bscatter_kernel<<<cdiv(E, CHUNK), 512, 0, stream>>>(src, dst, bcur, bsort, E);
    bbuild_kernel<<<NBUCK, 256, 0, stream>>>(bcur, bsort, csr, rowstart, rowdeg, dis,
                                             (const float4*)x, hQ, N);

    // --- mega1: hP = Z2 = dis*(relu(agg64(hQ)@W1+b1)@W2) ---
    mega1_kernel<<<cdiv(N, 16), 512, 0, stream>>>(
        hQ, rowstart, rowdeg, csr, dis, wt + 0, b1, wt + 6144, hP, N);

    // --- mega2: hQ = Z3 = dis*(relu(agg64(hP)+b2)@W3) ---
    mega2_kernel<<<cdiv(N, 16), 512, 0, stream>>>(
        hP, rowstart, rowdeg, csr, dis, b2, wt + 12288, hQ, N);

    // --- agg32+gemm4: hP = Z4 = dis*(relu(agg32(hQ)+b3)@W4) ---
    agg32_gemm4_kernel<<<cdiv(N, 16), 512, 0, stream>>>(
        hQ, rowstart, rowdeg, csr, dis, b3, wt + 14336, hP, N);

    // --- final: out = agg16(hP) + b4 (fp32) ---
    aggregate_final_kernel<<<cdiv(N, 16), TPB, 0, stream>>>(
        hP, rowstart, rowdeg, csr, dis, b4, out, N);
}